// Round 1
// baseline (5417.073 us; speedup 1.0000x reference)
//
#include <hip/hip_runtime.h>
#include <hip/hip_bf16.h>
#include <math.h>

#define NB 32
#define NN 320
#define ND 512
#define NINF 1e30f

// ---------------------------------------------------------------- K1: inverse norms
__global__ __launch_bounds__(64) void norm_kernel(const float* __restrict__ t,
                                                  float* __restrict__ s) {
    int row = blockIdx.x;
    const float4* p = (const float4*)(t + (size_t)row * ND);
    int tid = threadIdx.x;
    float4 a = p[tid];
    float4 b = p[tid + 64];
    float sum = a.x*a.x + a.y*a.y + a.z*a.z + a.w*a.w
              + b.x*b.x + b.y*b.y + b.z*b.z + b.w*b.w;
#pragma unroll
    for (int off = 32; off; off >>= 1) sum += __shfl_down(sum, off, 64);
    if (tid == 0) s[row] = 1.0f / fmaxf(sqrtf(sum), 1e-12f);
}

// ---------------------------------------------------------------- K2: cost = 1 - |n1 . n2|
// grid (25, NB): 5x5 tiles of 64x64; 256 threads, 4x4 per thread, BK=16.
__global__ __launch_bounds__(256) void cost_kernel(const float* __restrict__ t1,
                                                   const float* __restrict__ t2,
                                                   const float* __restrict__ s1,
                                                   const float* __restrict__ s2,
                                                   float* __restrict__ cost) {
    int b    = blockIdx.y;
    int tile = blockIdx.x;
    int bm0  = (tile / 5) * 64;
    int bn0  = (tile % 5) * 64;
    const float* A  = t1 + (size_t)b * NN * ND;
    const float* Bm = t2 + (size_t)b * NN * ND;
    float* C = cost + (size_t)b * NN * NN;

    __shared__ float As[16][64];
    __shared__ float Bs[16][64];

    int tid = threadIdx.x;
    int tx = tid & 15, ty = tid >> 4;
    int sm = tid >> 2;            // 0..63 staging row
    int skg = (tid & 3) * 4;      // k group

    float acc[4][4] = {};

    for (int k0 = 0; k0 < ND; k0 += 16) {
        float4 av = *(const float4*)(A  + (size_t)(bm0 + sm) * ND + k0 + skg);
        float4 bv = *(const float4*)(Bm + (size_t)(bn0 + sm) * ND + k0 + skg);
        __syncthreads();
        As[skg+0][sm] = av.x; As[skg+1][sm] = av.y; As[skg+2][sm] = av.z; As[skg+3][sm] = av.w;
        Bs[skg+0][sm] = bv.x; Bs[skg+1][sm] = bv.y; Bs[skg+2][sm] = bv.z; Bs[skg+3][sm] = bv.w;
        __syncthreads();
#pragma unroll
        for (int k = 0; k < 16; ++k) {
            float4 a4 = *(const float4*)&As[k][ty * 4];
            float4 b4 = *(const float4*)&Bs[k][tx * 4];
            float ar[4] = {a4.x, a4.y, a4.z, a4.w};
            float br[4] = {b4.x, b4.y, b4.z, b4.w};
#pragma unroll
            for (int r = 0; r < 4; ++r)
#pragma unroll
                for (int c = 0; c < 4; ++c)
                    acc[r][c] += ar[r] * br[c];
        }
    }

    float s2v[4];
#pragma unroll
    for (int c = 0; c < 4; ++c) s2v[c] = s2[b * NN + bn0 + tx * 4 + c];
#pragma unroll
    for (int r = 0; r < 4; ++r) {
        int gm = bm0 + ty * 4 + r;
        float s1v = s1[b * NN + gm];
        float4 o;
        o.x = 1.0f - fabsf(acc[r][0] * s1v * s2v[0]);
        o.y = 1.0f - fabsf(acc[r][1] * s1v * s2v[1]);
        o.z = 1.0f - fabsf(acc[r][2] * s1v * s2v[2]);
        o.w = 1.0f - fabsf(acc[r][3] * s1v * s2v[3]);
        *(float4*)(C + (size_t)gm * NN + bn0 + tx * 4) = o;
    }
}

// ---------------------------------------------------------------- block argmin (320 thr, 5 waves)
__device__ __forceinline__ void block_argmin(float val, int idx,
                                             float* red_v, int* red_i,
                                             float* sh_val, int* sh_idx, int tid) {
#pragma unroll
    for (int off = 32; off; off >>= 1) {
        float ov = __shfl_down(val, off, 64);
        int   oi = __shfl_down(idx, off, 64);
        if (ov < val || (ov == val && oi < idx)) { val = ov; idx = oi; }
    }
    if ((tid & 63) == 0) { red_v[tid >> 6] = val; red_i[tid >> 6] = idx; }
    __syncthreads();
    if (tid == 0) {
        float bv = red_v[0]; int bi = red_i[0];
#pragma unroll
        for (int w = 1; w < 5; ++w) {
            float ov = red_v[w]; int oi = red_i[w];
            if (ov < bv || (ov == bv && oi < bi)) { bv = ov; bi = oi; }
        }
        *sh_val = bv; *sh_idx = bi;
    }
    __syncthreads();
}

// ---------------------------------------------------------------- K3: JV / Hungarian, 1 block per batch
// Thread t owns (1-indexed) column t+1. v, minv, used live in registers.
__global__ __launch_bounds__(320) void lsa_kernel(const float* __restrict__ cost_all,
                                                  float* __restrict__ out) {
    int b = blockIdx.x;
    const float* C = cost_all + (size_t)b * NN * NN;
    int tid = threadIdx.x;

    __shared__ float u_lds[NN + 1];
    __shared__ int   p_lds[NN + 1];
    __shared__ int   way_lds[NN + 1];
    __shared__ int   assigned[NN + 1];
    __shared__ float red_v[5];
    __shared__ int   red_i[5];
    __shared__ float sh_val;
    __shared__ int   sh_idx;
    __shared__ int   sh_j0;

    for (int j = tid; j <= NN; j += NN) {
        u_lds[j] = 0.0f; p_lds[j] = 0; way_lds[j] = 0; assigned[j] = 0;
    }
    __syncthreads();

    // Phase A: column reduction. v[j] = min_i C[i][j] (feasible dual init).
    float v = NINF;
    for (int i = 0; i < NN; i += 4) {
        float c0 = C[(size_t)(i + 0) * NN + tid];
        float c1 = C[(size_t)(i + 1) * NN + tid];
        float c2 = C[(size_t)(i + 2) * NN + tid];
        float c3 = C[(size_t)(i + 3) * NN + tid];
        v = fminf(v, fminf(fminf(c0, c1), fminf(c2, c3)));
    }

    // Phase B: u[i] = min_j (C[i][j] - v[j]); greedy-assign when argmin column free.
    for (int r = 0; r < NN; ++r) {
        float red = C[(size_t)r * NN + tid] - v;
        block_argmin(red, tid + 1, red_v, red_i, &sh_val, &sh_idx, tid);
        if (tid == 0) {
            u_lds[r + 1] = sh_val;
            int jm = sh_idx;
            if (p_lds[jm] == 0) { p_lds[jm] = r + 1; assigned[r + 1] = 1; }
        }
    }
    __syncthreads();

    // Phase C: shortest augmenting path (reference's JV loop) for unassigned rows.
    for (int r = 0; r < NN; ++r) {
        if (assigned[r + 1]) continue;
        int i_row = r + 1;
        float minv = NINF;
        bool used = false;
        if (tid == 0) { p_lds[0] = i_row; sh_j0 = 0; }
        __syncthreads();
        int j1 = 0;
        while (1) {
            int j0 = sh_j0;
            if (tid + 1 == j0) used = true;
            int i0 = p_lds[j0];
            float cur = C[(size_t)(i0 - 1) * NN + tid] - u_lds[i0] - v;
            if (!used && cur < minv) { minv = cur; way_lds[tid + 1] = j0; }
            block_argmin(used ? NINF : minv, tid + 1, red_v, red_i, &sh_val, &sh_idx, tid);
            float delta = sh_val;
            j1 = sh_idx;
            if (tid == 0) u_lds[i_row] += delta;          // virtual column 0: p[0] = i_row
            if (used) { u_lds[p_lds[tid + 1]] += delta; v -= delta; }
            else      { minv -= delta; }
            int pj1 = p_lds[j1];
            if (tid == 0) sh_j0 = j1;
            __syncthreads();
            if (pj1 == 0) break;
        }
        // augment: walk the way[] chain (serial, thread 0)
        if (tid == 0) {
            int j = j1;
            while (j != 0) { int jp = way_lds[j]; p_lds[j] = p_lds[jp]; j = jp; }
        }
        __syncthreads();
    }

    // mean matched cost over columns
    float sum = C[(size_t)(p_lds[tid + 1] - 1) * NN + tid];
#pragma unroll
    for (int off = 32; off; off >>= 1) sum += __shfl_down(sum, off, 64);
    if ((tid & 63) == 0) red_v[tid >> 6] = sum;
    __syncthreads();
    if (tid == 0) {
        float t = red_v[0] + red_v[1] + red_v[2] + red_v[3] + red_v[4];
        out[b] = t / (float)NN;
    }
}

// ---------------------------------------------------------------- launch
extern "C" void kernel_launch(void* const* d_in, const int* in_sizes, int n_in,
                              void* d_out, int out_size, void* d_ws, size_t ws_size,
                              hipStream_t stream) {
    (void)in_sizes; (void)n_in; (void)out_size; (void)ws_size;
    const float* t1 = (const float*)d_in[0];
    const float* t2 = (const float*)d_in[1];
    float* out = (float*)d_out;

    float* s1   = (float*)d_ws;            // NB*NN
    float* s2   = s1 + NB * NN;            // NB*NN
    float* cost = s2 + NB * NN;            // NB*NN*NN

    norm_kernel<<<NB * NN, 64, 0, stream>>>(t1, s1);
    norm_kernel<<<NB * NN, 64, 0, stream>>>(t2, s2);
    cost_kernel<<<dim3(25, NB), 256, 0, stream>>>(t1, t2, s1, s2, cost);
    lsa_kernel<<<NB, NN, 0, stream>>>(cost, out);
}

// Round 4
// 4600.703 us; speedup vs baseline: 1.1774x; 1.1774x over previous
//
#include <hip/hip_runtime.h>
#include <hip/hip_bf16.h>
#include <math.h>

#define NB 32
#define NN 320
#define ND 512
#define KC 5            // columns per lane: 64 * 5 = 320
#define DINF 1e300

typedef unsigned long long u64;

// ---------------------------------------------------------------- K1: inverse norms
__global__ __launch_bounds__(64) void norm_kernel(const float* __restrict__ t,
                                                  float* __restrict__ s) {
    int row = blockIdx.x;
    const float4* p = (const float4*)(t + (size_t)row * ND);
    int tid = threadIdx.x;
    float4 a = p[tid];
    float4 b = p[tid + 64];
    float sum = a.x*a.x + a.y*a.y + a.z*a.z + a.w*a.w
              + b.x*b.x + b.y*b.y + b.z*b.z + b.w*b.w;
#pragma unroll
    for (int off = 32; off; off >>= 1) sum += __shfl_down(sum, off, 64);
    if (tid == 0) s[row] = 1.0f / fmaxf(sqrtf(sum), 1e-12f);
}

// ---------------------------------------------------------------- K2: cost = 1 - |n1 . n2|
__global__ __launch_bounds__(256) void cost_kernel(const float* __restrict__ t1,
                                                   const float* __restrict__ t2,
                                                   const float* __restrict__ s1,
                                                   const float* __restrict__ s2,
                                                   float* __restrict__ cost) {
    int b    = blockIdx.y;
    int tile = blockIdx.x;
    int bm0  = (tile / 5) * 64;
    int bn0  = (tile % 5) * 64;
    const float* A  = t1 + (size_t)b * NN * ND;
    const float* Bm = t2 + (size_t)b * NN * ND;
    float* C = cost + (size_t)b * NN * NN;

    __shared__ float As[16][64];
    __shared__ float Bs[16][64];

    int tid = threadIdx.x;
    int tx = tid & 15, ty = tid >> 4;
    int sm = tid >> 2;
    int skg = (tid & 3) * 4;

    float acc[4][4] = {};

    for (int k0 = 0; k0 < ND; k0 += 16) {
        float4 av = *(const float4*)(A  + (size_t)(bm0 + sm) * ND + k0 + skg);
        float4 bv = *(const float4*)(Bm + (size_t)(bn0 + sm) * ND + k0 + skg);
        __syncthreads();
        As[skg+0][sm] = av.x; As[skg+1][sm] = av.y; As[skg+2][sm] = av.z; As[skg+3][sm] = av.w;
        Bs[skg+0][sm] = bv.x; Bs[skg+1][sm] = bv.y; Bs[skg+2][sm] = bv.z; Bs[skg+3][sm] = bv.w;
        __syncthreads();
#pragma unroll
        for (int k = 0; k < 16; ++k) {
            float4 a4 = *(const float4*)&As[k][ty * 4];
            float4 b4 = *(const float4*)&Bs[k][tx * 4];
            float ar[4] = {a4.x, a4.y, a4.z, a4.w};
            float br[4] = {b4.x, b4.y, b4.z, b4.w};
#pragma unroll
            for (int r = 0; r < 4; ++r)
#pragma unroll
                for (int c = 0; c < 4; ++c)
                    acc[r][c] += ar[r] * br[c];
        }
    }

    float s2v[4];
#pragma unroll
    for (int c = 0; c < 4; ++c) s2v[c] = s2[b * NN + bn0 + tx * 4 + c];
#pragma unroll
    for (int r = 0; r < 4; ++r) {
        int gm = bm0 + ty * 4 + r;
        float s1v = s1[b * NN + gm];
        float4 o;
        o.x = 1.0f - fabsf(acc[r][0] * s1v * s2v[0]);
        o.y = 1.0f - fabsf(acc[r][1] * s1v * s2v[1]);
        o.z = 1.0f - fabsf(acc[r][2] * s1v * s2v[2]);
        o.w = 1.0f - fabsf(acc[r][3] * s1v * s2v[3]);
        *(float4*)(C + (size_t)gm * NN + bn0 + tx * 4) = o;
    }
}

// ---------------------------------------------------------------- sortable f64 key with idx in low 9 bits
// Reduced costs are always >= -eps (dual feasibility), so d+32 > 0 and the raw
// f64 bit pattern is order-preserving; low 9 mantissa bits carry the column idx.
__device__ __forceinline__ double key_make(double d, int idx1) {
    double s = fmax(d + 32.0, 0.0);
    long long b = __double_as_longlong(s);
    b = (b & ~511ll) | (long long)idx1;           // idx1 in 1..320 < 512
    return __longlong_as_double(b);
}
__device__ __forceinline__ int key_idx(double kd) {
    return (int)(__double_as_longlong(kd) & 511ll);
}
__device__ __forceinline__ double key_val(double kd) {
    return kd - 32.0;                              // ~1e-12 idx-bit perturbation, harmless
}

// ---------------------------------------------------------------- DPP wave-64 min (keys are positive doubles)
template<int CTRL>
__device__ __forceinline__ double dpp_min_step(double x) {
    long long b = __double_as_longlong(x);
    int lo = (int)(b & 0xffffffffll);
    int hi = (int)(b >> 32);
    int olo = __builtin_amdgcn_update_dpp(lo, lo, CTRL, 0xf, 0xf, false);
    int ohi = __builtin_amdgcn_update_dpp(hi, hi, CTRL, 0xf, 0xf, false);
    double o = __longlong_as_double(((long long)ohi << 32) | (unsigned)olo);
    return o < x ? o : x;
}

__device__ __forceinline__ double wave_min_key(double x) {
    x = dpp_min_step<0x111>(x);   // row_shr:1
    x = dpp_min_step<0x112>(x);   // row_shr:2
    x = dpp_min_step<0x114>(x);   // row_shr:4
    x = dpp_min_step<0x118>(x);   // row_shr:8  -> lanes 15/31/47/63 hold row mins
    x = dpp_min_step<0x142>(x);   // row_bcast:15 -> lane 31/63 fold prev row
    x = dpp_min_step<0x143>(x);   // row_bcast:31 -> lane 63 holds full min
    long long b = __double_as_longlong(x);
    int lo = __builtin_amdgcn_readlane((int)(b & 0xffffffffll), 63);
    int hi = __builtin_amdgcn_readlane((int)(b >> 32), 63);
    return __longlong_as_double(((long long)hi << 32) | (unsigned)lo);
}

// ---------------------------------------------------------------- K3: JV / Hungarian, 1 wave per batch
__global__ __launch_bounds__(64) void lsa_kernel(const float* __restrict__ cost_all,
                                                 float* __restrict__ out) {
    int b = blockIdx.x;
    const float* __restrict__ C = cost_all + (size_t)b * NN * NN;
    int t = threadIdx.x;

    __shared__ double u_lds[NN + 1];
    __shared__ int    p_lds[NN + 1];
    __shared__ int    way_lds[NN + 1];
    __shared__ int    assigned[NN + 1];

    for (int j = t; j <= NN; j += 64) {
        u_lds[j] = 0.0; p_lds[j] = 0; way_lds[j] = 0; assigned[j] = 0;
    }

    // Phase A: column minima -> v
    float vm[KC];
#pragma unroll
    for (int k = 0; k < KC; ++k) vm[k] = 1e30f;
#pragma unroll 4
    for (int i = 0; i < NN; ++i) {
        const float* row = C + (size_t)i * NN + t;
#pragma unroll
        for (int k = 0; k < KC; ++k) vm[k] = fminf(vm[k], row[64 * k]);
    }
    double v[KC];
#pragma unroll
    for (int k = 0; k < KC; ++k) v[k] = (double)vm[k];

    // Phase B: u[i] = min_j (C - v), greedy-assign free argmin columns
    {
        float f[KC], fn[KC];
#pragma unroll
        for (int k = 0; k < KC; ++k) f[k] = C[t + 64 * k];
        for (int r = 0; r < NN; ++r) {
            if (r + 1 < NN) {
                const float* nrow = C + (size_t)(r + 1) * NN + t;
#pragma unroll
                for (int k = 0; k < KC; ++k) fn[k] = nrow[64 * k];
            }
            double best = DINF;
#pragma unroll
            for (int k = 0; k < KC; ++k) {
                double cand = key_make((double)f[k] - v[k], t + 1 + 64 * k);
                best = cand < best ? cand : best;
            }
            best = wave_min_key(best);
            if (t == 0) {
                u_lds[r + 1] = key_val(best);
                int jm = key_idx(best);
                if (p_lds[jm] == 0) { p_lds[jm] = r + 1; assigned[r + 1] = 1; }
            }
            if (r + 1 < NN) {
#pragma unroll
                for (int k = 0; k < KC; ++k) f[k] = fn[k];
            }
        }
    }

    // Phase C: shortest augmenting path for unassigned rows (exact JV, f64 duals)
    for (int r = 0; r < NN; ++r) {
        if (assigned[r + 1]) continue;           // uniform
        const int i_row = r + 1;
        if (t == 0) p_lds[0] = i_row;            // virtual column 0 owner (augment walk reads it!)
        double u_irow = u_lds[i_row];
        double minv[KC];
        bool   used[KC];
        int    pown[KC];
#pragma unroll
        for (int k = 0; k < KC; ++k) { minv[k] = DINF; used[k] = false; pown[k] = 0; }
        int j0 = 0, j1 = 0;
        for (;;) {
            int i0; double ui0;
            if (j0 == 0) { i0 = i_row; ui0 = u_irow; }
            else         { i0 = p_lds[j0]; ui0 = u_lds[i0]; }
            const float* row = C + (size_t)(i0 - 1) * NN + t;
            float f[KC];
#pragma unroll
            for (int k = 0; k < KC; ++k) f[k] = row[64 * k];
            double best = DINF;
#pragma unroll
            for (int k = 0; k < KC; ++k) {
                double cur = (double)f[k] - ui0 - v[k];
                if (!used[k] && cur < minv[k]) { minv[k] = cur; way_lds[t + 1 + 64 * k] = j0; }
                double cand = used[k] ? DINF : key_make(minv[k], t + 1 + 64 * k);
                best = cand < best ? cand : best;
            }
            best = wave_min_key(best);
            double delta = key_val(best);
            j1 = key_idx(best);
            u_irow += delta;                     // virtual column 0 (p[0] = i_row)
#pragma unroll
            for (int k = 0; k < KC; ++k) {
                if (used[k]) { u_lds[pown[k]] += delta; v[k] -= delta; }
                else         { minv[k] -= delta; }
            }
            int pj1 = p_lds[j1];                 // uniform
            if (pj1 == 0) break;
#pragma unroll
            for (int k = 0; k < KC; ++k)
                if (t + 1 + 64 * k == j1) { used[k] = true; pown[k] = pj1; }
            j0 = j1;
        }
        if (t == 0) {
            u_lds[i_row] = u_irow;
            int j = j1;
            while (j != 0) { int jp = way_lds[j]; p_lds[j] = p_lds[jp]; j = jp; }
        }
    }

    // mean of matched costs
    double sum = 0.0;
#pragma unroll
    for (int k = 0; k < KC; ++k) {
        int c = t + 64 * k;
        int i = p_lds[c + 1] - 1;
        sum += (double)C[(size_t)i * NN + c];
    }
#pragma unroll
    for (int off = 32; off; off >>= 1) sum += __shfl_down(sum, off, 64);
    if (t == 0) out[b] = (float)(sum / (double)NN);
}

// ---------------------------------------------------------------- launch
extern "C" void kernel_launch(void* const* d_in, const int* in_sizes, int n_in,
                              void* d_out, int out_size, void* d_ws, size_t ws_size,
                              hipStream_t stream) {
    (void)in_sizes; (void)n_in; (void)out_size; (void)ws_size;
    const float* t1 = (const float*)d_in[0];
    const float* t2 = (const float*)d_in[1];
    float* out = (float*)d_out;

    float* s1   = (float*)d_ws;            // NB*NN
    float* s2   = s1 + NB * NN;            // NB*NN
    float* cost = s2 + NB * NN;            // NB*NN*NN

    norm_kernel<<<NB * NN, 64, 0, stream>>>(t1, s1);
    norm_kernel<<<NB * NN, 64, 0, stream>>>(t2, s2);
    cost_kernel<<<dim3(25, NB), 256, 0, stream>>>(t1, t2, s1, s2, cost);
    lsa_kernel<<<NB, 64, 0, stream>>>(cost, out);
}

// Round 5
// 2916.210 us; speedup vs baseline: 1.8576x; 1.5776x over previous
//
#include <hip/hip_runtime.h>
#include <hip/hip_bf16.h>
#include <math.h>

#define NB 32
#define NN 320
#define ND 512
#define KC 5            // columns per lane: 64 * 5 = 320
#define FINF 1e30f

// ---------------------------------------------------------------- K1: inverse norms
__global__ __launch_bounds__(64) void norm_kernel(const float* __restrict__ t,
                                                  float* __restrict__ s) {
    int row = blockIdx.x;
    const float4* p = (const float4*)(t + (size_t)row * ND);
    int tid = threadIdx.x;
    float4 a = p[tid];
    float4 b = p[tid + 64];
    float sum = a.x*a.x + a.y*a.y + a.z*a.z + a.w*a.w
              + b.x*b.x + b.y*b.y + b.z*b.z + b.w*b.w;
#pragma unroll
    for (int off = 32; off; off >>= 1) sum += __shfl_down(sum, off, 64);
    if (tid == 0) s[row] = 1.0f / fmaxf(sqrtf(sum), 1e-12f);
}

// ---------------------------------------------------------------- K2: cost = 1 - |n1 . n2|
__global__ __launch_bounds__(256) void cost_kernel(const float* __restrict__ t1,
                                                   const float* __restrict__ t2,
                                                   const float* __restrict__ s1,
                                                   const float* __restrict__ s2,
                                                   float* __restrict__ cost) {
    int b    = blockIdx.y;
    int tile = blockIdx.x;
    int bm0  = (tile / 5) * 64;
    int bn0  = (tile % 5) * 64;
    const float* A  = t1 + (size_t)b * NN * ND;
    const float* Bm = t2 + (size_t)b * NN * ND;
    float* C = cost + (size_t)b * NN * NN;

    __shared__ float As[16][64];
    __shared__ float Bs[16][64];

    int tid = threadIdx.x;
    int tx = tid & 15, ty = tid >> 4;
    int sm = tid >> 2;
    int skg = (tid & 3) * 4;

    float acc[4][4] = {};

    for (int k0 = 0; k0 < ND; k0 += 16) {
        float4 av = *(const float4*)(A  + (size_t)(bm0 + sm) * ND + k0 + skg);
        float4 bv = *(const float4*)(Bm + (size_t)(bn0 + sm) * ND + k0 + skg);
        __syncthreads();
        As[skg+0][sm] = av.x; As[skg+1][sm] = av.y; As[skg+2][sm] = av.z; As[skg+3][sm] = av.w;
        Bs[skg+0][sm] = bv.x; Bs[skg+1][sm] = bv.y; Bs[skg+2][sm] = bv.z; Bs[skg+3][sm] = bv.w;
        __syncthreads();
#pragma unroll
        for (int k = 0; k < 16; ++k) {
            float4 a4 = *(const float4*)&As[k][ty * 4];
            float4 b4 = *(const float4*)&Bs[k][tx * 4];
            float ar[4] = {a4.x, a4.y, a4.z, a4.w};
            float br[4] = {b4.x, b4.y, b4.z, b4.w};
#pragma unroll
            for (int r = 0; r < 4; ++r)
#pragma unroll
                for (int c = 0; c < 4; ++c)
                    acc[r][c] += ar[r] * br[c];
        }
    }

    float s2v[4];
#pragma unroll
    for (int c = 0; c < 4; ++c) s2v[c] = s2[b * NN + bn0 + tx * 4 + c];
#pragma unroll
    for (int r = 0; r < 4; ++r) {
        int gm = bm0 + ty * 4 + r;
        float s1v = s1[b * NN + gm];
        float4 o;
        o.x = 1.0f - fabsf(acc[r][0] * s1v * s2v[0]);
        o.y = 1.0f - fabsf(acc[r][1] * s1v * s2v[1]);
        o.z = 1.0f - fabsf(acc[r][2] * s1v * s2v[2]);
        o.w = 1.0f - fabsf(acc[r][3] * s1v * s2v[3]);
        *(float4*)(C + (size_t)gm * NN + bn0 + tx * 4) = o;
    }
}

// ---------------------------------------------------------------- f32 wave-64 min via DPP, result broadcast
template<int CTRL>
__device__ __forceinline__ float dpp_fmin(float x) {
    int xi = __float_as_int(x);
    int oi = __builtin_amdgcn_update_dpp(xi, xi, CTRL, 0xf, 0xf, false);
    return fminf(x, __int_as_float(oi));
}
__device__ __forceinline__ float wave_fmin_bcast(float x) {
    x = dpp_fmin<0x111>(x);   // row_shr:1
    x = dpp_fmin<0x112>(x);   // row_shr:2
    x = dpp_fmin<0x114>(x);   // row_shr:4
    x = dpp_fmin<0x118>(x);   // row_shr:8
    x = dpp_fmin<0x142>(x);   // row_bcast:15
    x = dpp_fmin<0x143>(x);   // row_bcast:31 -> lane 63 has the min
    return __int_as_float(__builtin_amdgcn_readlane(__float_as_int(x), 63));
}

// ---------------------------------------------------------------- K3: JV / Hungarian (lazy-delta), 1 wave per batch
__global__ __launch_bounds__(64) void lsa_kernel(const float* __restrict__ cost_all,
                                                 float* __restrict__ out) {
    int b = blockIdx.x;
    const float* __restrict__ C = cost_all + (size_t)b * NN * NN;
    int t = threadIdx.x;

    __shared__ float u_lds[NN + 1];
    __shared__ int   p_lds[NN + 1];
    __shared__ int   way_lds[NN + 1];
    __shared__ int   assigned[NN + 1];

    for (int j = t; j <= NN; j += 64) {
        u_lds[j] = 0.0f; p_lds[j] = 0; way_lds[j] = 0; assigned[j] = 0;
    }
    // single wave: LDS ops are in-order within the wave; no barrier needed

    // Phase A: column minima -> v  (feasible dual init)
    float v[KC];
#pragma unroll
    for (int k = 0; k < KC; ++k) v[k] = FINF;
#pragma unroll 4
    for (int i = 0; i < NN; ++i) {
        const float* row = C + (size_t)i * NN + t;
#pragma unroll
        for (int k = 0; k < KC; ++k) v[k] = fminf(v[k], row[64 * k]);
    }

    int preg[KC];                    // register mirror of p_lds[1..320]: lane t, reg k owns column t+1+64k
#pragma unroll
    for (int k = 0; k < KC; ++k) preg[k] = 0;

    // Phase B: u[i] = min_j (C[i][j] - v[j]); greedy-assign when argmin column free
    {
        float f[KC], fn[KC];
#pragma unroll
        for (int k = 0; k < KC; ++k) f[k] = C[t + 64 * k];
        for (int r = 0; r < NN; ++r) {
            if (r + 1 < NN) {
                const float* nrow = C + (size_t)(r + 1) * NN + t;
#pragma unroll
                for (int k = 0; k < KC; ++k) fn[k] = nrow[64 * k];
            }
            float bv = FINF; int bk = 0;
#pragma unroll
            for (int k = 0; k < KC; ++k) {
                float m = f[k] - v[k];
                if (m < bv) { bv = m; bk = k; }
            }
            float wmin = wave_fmin_bcast(bv);
            unsigned long long mask = __ballot(bv == wmin);
            int lsel = (int)__builtin_ctzll(mask);
            int jm = __builtin_amdgcn_readlane(t + 1 + (bk << 6), lsel);
            if (t == 0) u_lds[r + 1] = wmin;
            int jz = jm - 1, l2 = jz & 63, wh = jz >> 6;
            int pv = 0;
#pragma unroll
            for (int k = 0; k < KC; ++k) {
                int c = __builtin_amdgcn_readlane(preg[k], l2);
                if (wh == k) pv = c;
            }
            if (pv == 0) {
                if (t == 0) { p_lds[jm] = r + 1; assigned[r + 1] = 1; }
                if (l2 == t) {
#pragma unroll
                    for (int k = 0; k < KC; ++k) if (wh == k) preg[k] = r + 1;
                }
            }
            if (r + 1 < NN) {
#pragma unroll
                for (int k = 0; k < KC; ++k) f[k] = fn[k];
            }
        }
    }

    // Phase C: shortest augmenting path, scipy-form (duals static during each path)
    for (int r = 0; r < NN; ++r) {
        if (assigned[r + 1]) continue;          // uniform
        const int i_row = r + 1;
        if (t == 0) p_lds[0] = i_row;           // virtual column 0 owner for the augment walk
        float D[KC]; bool used[KC];
#pragma unroll
        for (int k = 0; k < KC; ++k) { D[k] = FINF; used[k] = false; }
        int i0 = i_row, curj = 0;
        float Dcur = 0.0f, minVal = 0.0f;
        int j1 = 0;
        for (;;) {
            const float* row = C + (size_t)(i0 - 1) * NN + t;
            float ui0 = u_lds[i0];              // broadcast LDS read, hidden under row loads
            float f[KC];
#pragma unroll
            for (int k = 0; k < KC; ++k) f[k] = row[64 * k];
            float s = Dcur - ui0;
            float bv = FINF; int bk = 0;
#pragma unroll
            for (int k = 0; k < KC; ++k) {
                if (!used[k]) {
                    float rr = f[k] + (s - v[k]);
                    if (rr < D[k]) { D[k] = rr; way_lds[t + 1 + (k << 6)] = curj; }
                    if (D[k] < bv) { bv = D[k]; bk = k; }
                }
            }
            float wmin = wave_fmin_bcast(bv);
            unsigned long long mask = __ballot(bv == wmin);
            int lsel = (int)__builtin_ctzll(mask);
            j1 = __builtin_amdgcn_readlane(t + 1 + (bk << 6), lsel);
            Dcur = wmin;
            int jz = j1 - 1, l2 = jz & 63, wh = jz >> 6;
            int pv = 0;
#pragma unroll
            for (int k = 0; k < KC; ++k) {
                int c = __builtin_amdgcn_readlane(preg[k], l2);
                if (wh == k) pv = c;
            }
            if (pv == 0) { minVal = wmin; break; }   // sink: j1 is unassigned
            {
                bool me = (l2 == t);
#pragma unroll
                for (int k = 0; k < KC; ++k) if (me && wh == k) used[k] = true;
            }
            i0 = pv; curj = j1;
        }
        // one-shot dual updates: v[j] -= (minVal - D[j]); u[p[j]] += (minVal - D[j]) for used j
#pragma unroll
        for (int k = 0; k < KC; ++k) {
            if (used[k]) {
                float adj = minVal - D[k];
                v[k] -= adj;
                u_lds[preg[k]] += adj;          // owner rows distinct: no collisions
            }
        }
        if (t == 0) {
            u_lds[i_row] += minVal;
            int j = j1;                          // augment walk
            while (j != 0) { int jp = way_lds[j]; p_lds[j] = p_lds[jp]; j = jp; }
        }
#pragma unroll
        for (int k = 0; k < KC; ++k) preg[k] = p_lds[t + 1 + (k << 6)];  // refresh mirror
    }

    // mean of matched costs
    double sum = 0.0;
#pragma unroll
    for (int k = 0; k < KC; ++k) {
        int c = t + 64 * k;
        int i = p_lds[c + 1] - 1;
        sum += (double)C[(size_t)i * NN + c];
    }
#pragma unroll
    for (int off = 32; off; off >>= 1) sum += __shfl_down(sum, off, 64);
    if (t == 0) out[b] = (float)(sum / (double)NN);
}

// ---------------------------------------------------------------- launch
extern "C" void kernel_launch(void* const* d_in, const int* in_sizes, int n_in,
                              void* d_out, int out_size, void* d_ws, size_t ws_size,
                              hipStream_t stream) {
    (void)in_sizes; (void)n_in; (void)out_size; (void)ws_size;
    const float* t1 = (const float*)d_in[0];
    const float* t2 = (const float*)d_in[1];
    float* out = (float*)d_out;

    float* s1   = (float*)d_ws;            // NB*NN
    float* s2   = s1 + NB * NN;            // NB*NN
    float* cost = s2 + NB * NN;            // NB*NN*NN

    norm_kernel<<<NB * NN, 64, 0, stream>>>(t1, s1);
    norm_kernel<<<NB * NN, 64, 0, stream>>>(t2, s2);
    cost_kernel<<<dim3(25, NB), 256, 0, stream>>>(t1, t2, s1, s2, cost);
    lsa_kernel<<<NB, 64, 0, stream>>>(cost, out);
}

// Round 8
// 2781.517 us; speedup vs baseline: 1.9475x; 1.0484x over previous
//
#include <hip/hip_runtime.h>
#include <hip/hip_bf16.h>
#include <math.h>

#define NB 32
#define NN 320
#define ND 512
#define KC 5            // columns per lane: 64 * 5 = 320
#define FINF 1e30f

// ---------------------------------------------------------------- K1: inverse norms
__global__ __launch_bounds__(64) void norm_kernel(const float* __restrict__ t,
                                                  float* __restrict__ s) {
    int row = blockIdx.x;
    const float4* p = (const float4*)(t + (size_t)row * ND);
    int tid = threadIdx.x;
    float4 a = p[tid];
    float4 b = p[tid + 64];
    float sum = a.x*a.x + a.y*a.y + a.z*a.z + a.w*a.w
              + b.x*b.x + b.y*b.y + b.z*b.z + b.w*b.w;
#pragma unroll
    for (int off = 32; off; off >>= 1) sum += __shfl_down(sum, off, 64);
    if (tid == 0) s[row] = 1.0f / fmaxf(sqrtf(sum), 1e-12f);
}

// ---------------------------------------------------------------- K2: cost = 1 - |n1 . n2|
__global__ __launch_bounds__(256) void cost_kernel(const float* __restrict__ t1,
                                                   const float* __restrict__ t2,
                                                   const float* __restrict__ s1,
                                                   const float* __restrict__ s2,
                                                   float* __restrict__ cost) {
    int b    = blockIdx.y;
    int tile = blockIdx.x;
    int bm0  = (tile / 5) * 64;
    int bn0  = (tile % 5) * 64;
    const float* A  = t1 + (size_t)b * NN * ND;
    const float* Bm = t2 + (size_t)b * NN * ND;
    float* C = cost + (size_t)b * NN * NN;

    __shared__ float As[16][64];
    __shared__ float Bs[16][64];

    int tid = threadIdx.x;
    int tx = tid & 15, ty = tid >> 4;
    int sm = tid >> 2;
    int skg = (tid & 3) * 4;

    float acc[4][4] = {};

    for (int k0 = 0; k0 < ND; k0 += 16) {
        float4 av = *(const float4*)(A  + (size_t)(bm0 + sm) * ND + k0 + skg);
        float4 bv = *(const float4*)(Bm + (size_t)(bn0 + sm) * ND + k0 + skg);
        __syncthreads();
        As[skg+0][sm] = av.x; As[skg+1][sm] = av.y; As[skg+2][sm] = av.z; As[skg+3][sm] = av.w;
        Bs[skg+0][sm] = bv.x; Bs[skg+1][sm] = bv.y; Bs[skg+2][sm] = bv.z; Bs[skg+3][sm] = bv.w;
        __syncthreads();
#pragma unroll
        for (int k = 0; k < 16; ++k) {
            float4 a4 = *(const float4*)&As[k][ty * 4];
            float4 b4 = *(const float4*)&Bs[k][tx * 4];
            float ar[4] = {a4.x, a4.y, a4.z, a4.w};
            float br[4] = {b4.x, b4.y, b4.z, b4.w};
#pragma unroll
            for (int r = 0; r < 4; ++r)
#pragma unroll
                for (int c = 0; c < 4; ++c)
                    acc[r][c] += ar[r] * br[c];
        }
    }

    float s2v[4];
#pragma unroll
    for (int c = 0; c < 4; ++c) s2v[c] = s2[b * NN + bn0 + tx * 4 + c];
#pragma unroll
    for (int r = 0; r < 4; ++r) {
        int gm = bm0 + ty * 4 + r;
        float s1v = s1[b * NN + gm];
        float4 o;
        o.x = 1.0f - fabsf(acc[r][0] * s1v * s2v[0]);
        o.y = 1.0f - fabsf(acc[r][1] * s1v * s2v[1]);
        o.z = 1.0f - fabsf(acc[r][2] * s1v * s2v[2]);
        o.w = 1.0f - fabsf(acc[r][3] * s1v * s2v[3]);
        *(float4*)(C + (size_t)gm * NN + bn0 + tx * 4) = o;
    }
}

// ---------------------------------------------------------------- f32 wave-64 min via DPP
template<int CTRL>
__device__ __forceinline__ float dpp_fmin(float x) {
    int xi = __float_as_int(x);
    int oi = __builtin_amdgcn_update_dpp(xi, xi, CTRL, 0xf, 0xf, false);
    return fminf(x, __int_as_float(oi));
}
__device__ __forceinline__ float wave_fmin_bcast(float x) {
    x = dpp_fmin<0x111>(x);   // row_shr:1
    x = dpp_fmin<0x112>(x);   // row_shr:2
    x = dpp_fmin<0x114>(x);   // row_shr:4
    x = dpp_fmin<0x118>(x);   // row_shr:8
    x = dpp_fmin<0x142>(x);   // row_bcast:15
    x = dpp_fmin<0x143>(x);   // row_bcast:31 -> lane 63 has the min
    return __int_as_float(__builtin_amdgcn_readlane(__float_as_int(x), 63));
}

// ---------------------------------------------------------------- K3: JV / Hungarian, 1 wave per batch
__global__ __launch_bounds__(64) void lsa_kernel(const float* __restrict__ cost_all,
                                                 float* __restrict__ out) {
    int b = blockIdx.x;
    const float* __restrict__ C = cost_all + (size_t)b * NN * NN;
    int t = threadIdx.x;

    __shared__ float u_lds[NN + 1];
    __shared__ int   p_lds[NN + 1];
    __shared__ int   way_lds[NN + 1];
    __shared__ int   assigned[NN + 1];

    for (int j = t; j <= NN; j += 64) {
        u_lds[j] = 0.0f; p_lds[j] = 0; way_lds[j] = 0; assigned[j] = 0;
    }
    __syncthreads();

    // Phase A: column minima -> v (feasible dual init)
    float v[KC];
#pragma unroll
    for (int k = 0; k < KC; ++k) v[k] = FINF;
#pragma unroll 4
    for (int i = 0; i < NN; ++i) {
        const float* row = C + (size_t)i * NN + t;
#pragma unroll
        for (int k = 0; k < KC; ++k) v[k] = fminf(v[k], row[64 * k]);
    }

    int preg[KC];                    // register mirror of p_lds[1..320]: lane t, reg k owns col t+1+64k
#pragma unroll
    for (int k = 0; k < KC; ++k) preg[k] = 0;

    // Phase B: u[i] = min_j (C[i][j] - v[j]); greedy-assign when argmin column free
    {
        float f[KC], fn[KC];
#pragma unroll
        for (int k = 0; k < KC; ++k) f[k] = C[t + 64 * k];
        for (int r = 0; r < NN; ++r) {
            if (r + 1 < NN) {
                const float* nrow = C + (size_t)(r + 1) * NN + t;
#pragma unroll
                for (int k = 0; k < KC; ++k) fn[k] = nrow[64 * k];
            }
            float bv = FINF; int bk = 0;
#pragma unroll
            for (int k = 0; k < KC; ++k) {
                float m = f[k] - v[k];
                if (m < bv) { bv = m; bk = k; }
            }
            float wmin = wave_fmin_bcast(bv);
            unsigned long long mask = __ballot(bv == wmin);
            int lsel = mask ? (int)__builtin_ctzll(mask) : 0;
            int jm = __builtin_amdgcn_readlane(t + 1 + (bk << 6), lsel);
            if (t == 0) u_lds[r + 1] = wmin;
            int jz = jm - 1, l2 = jz & 63, wh = jz >> 6;
            int pv = 0;
#pragma unroll
            for (int k = 0; k < KC; ++k) {
                int c = __builtin_amdgcn_readlane(preg[k], l2);
                if (wh == k) pv = c;
            }
            if (pv == 0) {
                if (t == 0) { p_lds[jm] = r + 1; assigned[r + 1] = 1; }
                if (l2 == t) {
#pragma unroll
                    for (int k = 0; k < KC; ++k) if (wh == k) preg[k] = r + 1;
                }
            }
            if (r + 1 < NN) {
#pragma unroll
                for (int k = 0; k < KC; ++k) f[k] = fn[k];
            }
        }
    }
    __syncthreads();

    // Phase B2: JV augmenting row reduction, 2 budgeted passes (hardened).
    // Invariants per assignment: u[i]=wm2, v[j1]-=adj => arc (i,j1) tight,
    // all reduced costs stay >= 0. Displaced row continues the chain.
    for (int pass = 0; pass < 2; ++pass) {
        int budget = 2 * NN;
        for (int r0 = 1; r0 <= NN; ++r0) {
            if (assigned[r0]) continue;       // uniform LDS read (fenced by barriers below)
            int i = r0;
            while (i != 0 && --budget >= 0) {
                const float* row = C + (size_t)(i - 1) * NN + t;
                float lm1 = FINF, lm2 = FINF; int bk = 0;
#pragma unroll
                for (int k = 0; k < KC; ++k) {
                    float m = row[64 * k] - v[k];
                    if (m < lm1) { lm2 = lm1; lm1 = m; bk = k; }
                    else         { lm2 = fminf(lm2, m); }
                }
                float wm1 = wave_fmin_bcast(lm1);
                unsigned long long mask = __ballot(lm1 == wm1);
                if (!mask) break;             // rail (cannot happen)
                int lsel = (int)__builtin_ctzll(mask);
                int j1 = __builtin_amdgcn_readlane(t + 1 + (bk << 6), lsel);
                float wm2 = wave_fmin_bcast((t == lsel) ? lm2 : lm1);
                float adj = wm2 - wm1;        // >= 0
                if (j1 < 1 || j1 > NN) break; // rail (cannot happen)
                int jz = j1 - 1, l2 = jz & 63, wh = jz >> 6;
                int pv = 0;
#pragma unroll
                for (int k = 0; k < KC; ++k) {
                    int c = __builtin_amdgcn_readlane(preg[k], l2);
                    if (wh == k) pv = c;
                }
                if (pv < 0 || pv > NN) pv = 0;  // rail (cannot happen)
                if (t == 0) u_lds[i] = wm2;     // feasible in both branches (adj==0 on abandon)
                if (pv == 0 || adj > 0.0f) {
                    if (t == 0) {
                        p_lds[j1] = i; assigned[i] = 1;
                        if (pv) assigned[pv] = 0;
                    }
                    if (t == l2) {
#pragma unroll
                        for (int k = 0; k < KC; ++k) if (wh == k) {
                            preg[k] = i;
                            v[k] -= adj;        // always on assign
                        }
                    }
                    i = pv;                   // displaced row continues (0 if col was free)
                } else {
                    i = 0;                    // exact tie on occupied column: leave for Phase C
                }
                __syncthreads();              // fence LDS mutations (1 wave: cannot deadlock)
            }
        }
        __syncthreads();
    }

    // Phase C: shortest augmenting path, scipy-form (duals static during each path)
    for (int r = 0; r < NN; ++r) {
        if (assigned[r + 1]) continue;          // uniform
        const int i_row = r + 1;
        if (t == 0) p_lds[0] = i_row;           // virtual column 0 owner for the augment walk
        float D[KC]; bool used[KC];
#pragma unroll
        for (int k = 0; k < KC; ++k) { D[k] = FINF; used[k] = false; }
        int i0 = i_row, curj = 0;
        float Dcur = 0.0f, minVal = 0.0f;
        int j1 = 0;
        bool okpath = false;
        for (int step = 0; step <= NN; ++step) {
            const float* row = C + (size_t)(i0 - 1) * NN + t;
            float ui0 = u_lds[i0];              // broadcast read, hidden under row loads
            float f[KC];
#pragma unroll
            for (int k = 0; k < KC; ++k) f[k] = row[64 * k];
            float s = Dcur - ui0;
            float bv = FINF; int bk = 0;
#pragma unroll
            for (int k = 0; k < KC; ++k) {
                if (!used[k]) {
                    float rr = f[k] + (s - v[k]);
                    if (rr < D[k]) { D[k] = rr; way_lds[t + 1 + (k << 6)] = curj; }
                    if (D[k] < bv) { bv = D[k]; bk = k; }
                }
            }
            float wmin = wave_fmin_bcast(bv);
            unsigned long long mask = __ballot(bv == wmin);
            int lsel = mask ? (int)__builtin_ctzll(mask) : 0;
            j1 = __builtin_amdgcn_readlane(t + 1 + (bk << 6), lsel);
            if (j1 < 1 || j1 > NN) break;        // rail -> okpath stays false
            Dcur = wmin;
            int jz = j1 - 1, l2 = jz & 63, wh = jz >> 6;
            int pv = 0;
#pragma unroll
            for (int k = 0; k < KC; ++k) {
                int c = __builtin_amdgcn_readlane(preg[k], l2);
                if (wh == k) pv = c;
            }
            if (pv <= 0 || pv > NN) { minVal = wmin; okpath = true; break; }  // sink
            {
                bool me = (l2 == t);
#pragma unroll
                for (int k = 0; k < KC; ++k) if (me && wh == k) used[k] = true;
            }
            i0 = pv; curj = j1;
        }
        if (okpath) {
            // one-shot dual updates
#pragma unroll
            for (int k = 0; k < KC; ++k) {
                if (used[k]) {
                    float adj = minVal - D[k];
                    v[k] -= adj;
                    u_lds[preg[k]] += adj;      // owner rows distinct: no collisions
                }
            }
            if (t == 0) {
                u_lds[i_row] += minVal;
                int j = j1;                      // augment walk (way chain acyclic, this-round only)
                int guard = NN + 1;
                while (j != 0 && --guard >= 0) { int jp = way_lds[j]; p_lds[j] = p_lds[jp]; j = jp; }
            }
        }
        __syncthreads();
#pragma unroll
        for (int k = 0; k < KC; ++k) preg[k] = p_lds[t + 1 + (k << 6)];  // refresh mirror
    }
    __syncthreads();

    // mean of matched costs (self-assign fallback keeps indices in-bounds)
    double sum = 0.0;
#pragma unroll
    for (int k = 0; k < KC; ++k) {
        int c = t + 64 * k;
        int p = p_lds[c + 1];
        if (p < 1 || p > NN) p = c + 1;
        sum += (double)C[(size_t)(p - 1) * NN + c];
    }
#pragma unroll
    for (int off = 32; off; off >>= 1) sum += __shfl_down(sum, off, 64);
    if (t == 0) out[b] = (float)(sum / (double)NN);
}

// ---------------------------------------------------------------- launch
extern "C" void kernel_launch(void* const* d_in, const int* in_sizes, int n_in,
                              void* d_out, int out_size, void* d_ws, size_t ws_size,
                              hipStream_t stream) {
    (void)in_sizes; (void)n_in; (void)out_size; (void)ws_size;
    const float* t1 = (const float*)d_in[0];
    const float* t2 = (const float*)d_in[1];
    float* out = (float*)d_out;

    float* s1   = (float*)d_ws;            // NB*NN
    float* s2   = s1 + NB * NN;            // NB*NN
    float* cost = s2 + NB * NN;            // NB*NN*NN

    norm_kernel<<<NB * NN, 64, 0, stream>>>(t1, s1);
    norm_kernel<<<NB * NN, 64, 0, stream>>>(t2, s2);
    cost_kernel<<<dim3(25, NB), 256, 0, stream>>>(t1, t2, s1, s2, cost);
    lsa_kernel<<<NB, 64, 0, stream>>>(cost, out);
}